// Round 1
// 299.334 us; speedup vs baseline: 1.0555x; 1.0555x over previous
//
#include <hip/hip_runtime.h>
#include <math.h>

// Problem constants
#define B_    4
#define L_    1024
#define D_    768
#define H_    12
#define NE_   42
#define M_    8
#define NE2_  (NE_ * NE_)      // 1764
#define NTRI_ 903              // 42*43/2 unique (s<=t) pairs (output is symmetric!)
#define MPAD_ 1024             // packed-tri rows padded to 8*128 for GEMM tiles
#define LC_   16               // l-chunk per gram block
#define NCH_  (L_ / LC_)       // 64 chunks

typedef unsigned short u16;
typedef unsigned int   u32;
typedef __attribute__((ext_vector_type(2))) float f32x2;

__device__ __forceinline__ u16 f2bf(float f) {
    union { float f; u32 u; } c; c.f = f;
    u32 u = c.u;
    u32 r = (u + 0x7FFFu + ((u >> 16) & 1u)) >> 16;  // round-to-nearest-even
    return (u16)r;
}

// ---------------------------------------------------------------------------
// Kernel 1: ent_att[b,h,e,l] = (1/cnt) * sum_{valid m} attention[b,h,idx+1,l]
// grid (H, NE, B), 128 threads; thread t covers l = t*8 .. t*8+7
// ---------------------------------------------------------------------------
__global__ __launch_bounds__(128) void ent_att_kernel(
    const float* __restrict__ att, const int* __restrict__ midx,
    const int* __restrict__ mmask, float* __restrict__ ent) {
    const int h = blockIdx.x, e = blockIdx.y, b = blockIdx.z;
    const int t  = threadIdx.x;
    const int l0 = t * 8;
    const int mb = (b * NE_ + e) * M_;
    const size_t abase = ((size_t)(b * H_ + h)) * L_ * L_;

    float acc[8] = {0.f,0.f,0.f,0.f,0.f,0.f,0.f,0.f};
    int cnt = 0;
    for (int m = 0; m < M_; ++m) {
        int  im = midx[mb + m] + 1;                       // OFFSET = 1
        bool v  = (mmask[mb + m] > 0) && (im < L_);
        if (v) {
            ++cnt;
            const float* row = att + abase + (size_t)im * L_ + l0;
            float4 x0 = *(const float4*)(row);
            float4 x1 = *(const float4*)(row + 4);
            acc[0] += x0.x; acc[1] += x0.y; acc[2] += x0.z; acc[3] += x0.w;
            acc[4] += x1.x; acc[5] += x1.y; acc[6] += x1.z; acc[7] += x1.w;
        }
    }
    const float s = 1.0f / (float)(cnt < 1 ? 1 : cnt);
    float* o = ent + (((size_t)(b * H_ + h)) * NE_ + e) * L_ + l0;
    *(float4*)(o)     = make_float4(acc[0]*s, acc[1]*s, acc[2]*s, acc[3]*s);
    *(float4*)(o + 4) = make_float4(acc[4]*s, acc[5]*s, acc[6]*s, acc[7]*s);
}

// ---------------------------------------------------------------------------
// Kernel 2: transpose+convert sequence_output f32 [b][k=L][n=D] -> ST bf16
// [b][n=D][k=L]. grid (D/32, L/32, B), block (32,8)
// ---------------------------------------------------------------------------
__global__ __launch_bounds__(256) void transpose_kernel(
    const float* __restrict__ S, u16* __restrict__ T) {
    __shared__ u16 tile[32][33];
    const int b  = blockIdx.z;
    const int n0 = blockIdx.x * 32;
    const int k0 = blockIdx.y * 32;
    const int tx = threadIdx.x, ty = threadIdx.y;
    const float* Sb = S + (size_t)b * L_ * D_;
    u16*         Tb = T + (size_t)b * D_ * L_;
    #pragma unroll
    for (int i = 0; i < 4; ++i)
        tile[ty + i*8][tx] = f2bf(Sb[(size_t)(k0 + ty + i*8) * D_ + (n0 + tx)]);
    __syncthreads();
    #pragma unroll
    for (int i = 0; i < 4; ++i)
        Tb[(size_t)(n0 + ty + i*8) * L_ + (k0 + tx)] = tile[tx][ty + i*8];
}

// ---------------------------------------------------------------------------
// Kernel 3 (NEW): gram_kernel. One block per (b, l-chunk of 16). Stages
// E[b,:,:,l0:l0+16] (32 KB) in LDS ONCE and computes the UNNORMALIZED Gram
// G[s,t,l] = sum_h E[h,s,l]*E[h,t,l] for ALL upper-triangle pairs s<=t,
// packed as row q = s*(85-s)/2 + (t-s) in W (bf16), plus f32 per-chunk
// partial row-sums (psum) for the GEMM-epilogue normalization.
// Replaces the old w_kernel's 677 MB of L2 re-reads with 8.3 MB read-once.
// grid 256 blocks (XCD-swizzled so W cache lines stay XCD-local), 256 thr.
// ---------------------------------------------------------------------------
__global__ __launch_bounds__(256) void gram_kernel(
    const float* __restrict__ ent,   // [B][H][NE][L] f32
    u16* __restrict__ W,             // [B][MPAD_][L] bf16, unnormalized packed-tri
    float* __restrict__ psum)        // [B][MPAD_][NCH_] f32 partial row sums
{
    __shared__ float E[H_ * NE_ * 18 + 8];   // [row=h*42+e][l: 16 used, pad to 18]
    // bijective XCD swizzle: XCD x owns 8 consecutive chunks for all 4 b
    const int gid   = blockIdx.x;            // 0..255
    const int xcd   = gid & 7, rr = gid >> 3;
    const int chunk = xcd * 8 + (rr & 7);    // 0..63
    const int b     = rr >> 3;               // 0..3
    const int l0    = chunk * LC_;
    const int tid   = threadIdx.x;

    // ---- stage: 504 rows x 16 floats, write as f32x2 (stride 18 keeps 8B align)
    const float* Eb = ent + (size_t)b * (H_ * NE_) * L_ + l0;
    for (int i = tid; i < H_ * NE_ * 4; i += 256) {
        const int row = i >> 2, sub = (i & 3) * 4;
        float4 v = *(const float4*)(Eb + (size_t)row * L_ + sub);
        f32x2* d = (f32x2*)&E[row * 18 + sub];
        d[0] = f32x2{v.x, v.y};
        d[1] = f32x2{v.z, v.w};
    }
    __syncthreads();

    if (tid < 231) {
        // pair tile: 2 s-values x 4 t-values; 21 x 11 tiles cover 42 x 44
        const int st = tid % 21, tt = tid / 21;
        const int s0 = 2 * st, t0 = 4 * tt;
        if (s0 <= t0 + 3) {                      // tile intersects upper triangle
            const int e2 = (t0 + 2 < NE_) ? t0 + 2 : NE_ - 1;  // clamp (guarded on emit)
            const int e3 = (t0 + 3 < NE_) ? t0 + 3 : NE_ - 1;
            float ps[2][4] = {};
            for (int l2 = 0; l2 < LC_ / 2; ++l2) {
                const int ll = 2 * l2;
                f32x2 c[2][4] = {};
                #pragma unroll
                for (int h = 0; h < H_; ++h) {
                    const float* Eh = E + h * (NE_ * 18);
                    f32x2 a0 = *(const f32x2*)&Eh[(s0    ) * 18 + ll];
                    f32x2 a1 = *(const f32x2*)&Eh[(s0 + 1) * 18 + ll];
                    f32x2 b0 = *(const f32x2*)&Eh[(t0    ) * 18 + ll];
                    f32x2 b1 = *(const f32x2*)&Eh[(t0 + 1) * 18 + ll];
                    f32x2 b2 = *(const f32x2*)&Eh[(e2    ) * 18 + ll];
                    f32x2 b3 = *(const f32x2*)&Eh[(e3    ) * 18 + ll];
                    c[0][0] += a0 * b0; c[0][1] += a0 * b1;
                    c[0][2] += a0 * b2; c[0][3] += a0 * b3;
                    c[1][0] += a1 * b0; c[1][1] += a1 * b1;
                    c[1][2] += a1 * b2; c[1][3] += a1 * b3;
                }
                #pragma unroll
                for (int si = 0; si < 2; ++si) {
                    #pragma unroll
                    for (int tj = 0; tj < 4; ++tj) {
                        const int s = s0 + si, t = t0 + tj;
                        if (t < NE_ && s <= t) {
                            const int q = (s * (85 - s)) / 2 + (t - s);
                            u32 w = (u32)f2bf(c[si][tj][0]) |
                                    ((u32)f2bf(c[si][tj][1]) << 16);
                            *(u32*)(W + ((size_t)b * MPAD_ + q) * L_ + l0 + ll) = w;
                            ps[si][tj] += c[si][tj][0] + c[si][tj][1];
                        }
                    }
                }
            }
            #pragma unroll
            for (int si = 0; si < 2; ++si)
                #pragma unroll
                for (int tj = 0; tj < 4; ++tj) {
                    const int s = s0 + si, t = t0 + tj;
                    if (t < NE_ && s <= t) {
                        const int q = (s * (85 - s)) / 2 + (t - s);
                        psum[((size_t)b * MPAD_ + q) * NCH_ + chunk] = ps[si][tj];
                    }
                }
        }
    } else {
        // zero the 121 GEMM pad rows (903..1023) for this l-chunk; 25 threads
        for (int q = NTRI_ + (tid - 231); q < MPAD_; q += 25) {
            u16* wr = W + ((size_t)b * MPAD_ + q) * L_ + l0;
            uint4 z; z.x = z.y = z.z = z.w = 0u;
            *(uint4*)(wr)     = z;
            *(uint4*)(wr + 8) = z;
        }
    }
}

// ---------------------------------------------------------------------------
// Kernel 3b (NEW): rscale[b][q] = 1/(sum_chunks psum + H*1e-5). Deterministic
// f32 reduction of the pre-bf16 accumulators (same numeric path as before).
// ---------------------------------------------------------------------------
__global__ __launch_bounds__(256) void rscale_kernel(
    const float* __restrict__ psum, float* __restrict__ rscale) {
    const int g = blockIdx.x * 256 + threadIdx.x;
    if (g >= B_ * NTRI_) return;
    const int b = g / NTRI_, q = g % NTRI_;
    const float* p = psum + ((size_t)b * MPAD_ + q) * NCH_;
    float s = 0.f;
    #pragma unroll
    for (int i = 0; i < NCH_; ++i) s += p[i];
    rscale[b * MPAD_ + q] = 1.0f / (s + (float)H_ * 1e-5f);
}

// ---------------------------------------------------------------------------
// Kernel 4: batched GEMM out = diag(rscale) * (W_packed @ S), bf16 MFMA.
// M packed to 1024 tri rows -> grid (8, 6, B) = 192 blocks = ONE scheduling
// wave on 256 CUs (was 336 = 2 waves with a 49%-idle tail).
// Epilogue recovers (s,t) from q and writes BOTH symmetric outputs.
// ---------------------------------------------------------------------------
typedef __attribute__((ext_vector_type(8))) __bf16 bf16x8;
typedef __attribute__((ext_vector_type(4))) float  f32x4;

__global__ __launch_bounds__(256) void gemm_kernel(
    const u16* __restrict__ W, const u16* __restrict__ T,
    const float* __restrict__ rscale, float* __restrict__ out) {
    __shared__ __align__(16) u16 As[128 * 32];
    __shared__ __align__(16) u16 Bs[128 * 32];
    const int b = blockIdx.z;
    const u16* Ab = W + (size_t)b * MPAD_ * L_ + (size_t)blockIdx.x * 128 * L_;
    const u16* Bb = T + (size_t)b * D_   * L_ + (size_t)blockIdx.y * 128 * L_;
    const int tid  = threadIdx.x;
    const int wave = tid >> 6, lane = tid & 63;
    const int wm = (wave & 1) * 64, wn = (wave >> 1) * 64;
    const int rm = lane & 15, kq = (lane >> 4) * 8;

    f32x4 acc[4][4] = {};

    for (int k0 = 0; k0 < L_; k0 += 32) {
        __syncthreads();   // prior iteration's frag reads done before overwrite
        #pragma unroll
        for (int i = 0; i < 2; ++i) {
            int c = i * 256 + tid;            // 512 chunks of 16B = 8KB tile
            int row = c >> 2, ko = (c & 3) * 8;
            __builtin_amdgcn_global_load_lds(
                (const __attribute__((address_space(1))) void*)(Ab + (size_t)row * L_ + k0 + ko),
                (__attribute__((address_space(3))) void*)(&As[c * 8]), 16, 0, 0);
            __builtin_amdgcn_global_load_lds(
                (const __attribute__((address_space(1))) void*)(Bb + (size_t)row * L_ + k0 + ko),
                (__attribute__((address_space(3))) void*)(&Bs[c * 8]), 16, 0, 0);
        }
        __syncthreads();   // drains vmcnt (global_load_lds) per barrier semantics

        bf16x8 af[4], bfr[4];
        #pragma unroll
        for (int i = 0; i < 4; ++i)
            af[i]  = *(const bf16x8*)&As[(wm + i*16 + rm) * 32 + kq];
        #pragma unroll
        for (int j = 0; j < 4; ++j)
            bfr[j] = *(const bf16x8*)&Bs[(wn + j*16 + rm) * 32 + kq];
        #pragma unroll
        for (int i = 0; i < 4; ++i)
            #pragma unroll
            for (int j = 0; j < 4; ++j)
                acc[i][j] = __builtin_amdgcn_mfma_f32_16x16x32_bf16(
                                af[i], bfr[j], acc[i][j], 0, 0, 0);
    }

    // Epilogue: C/D layout col = lane&15, row = (lane>>4)*4 + reg (m89/m91).
    // Row q is a packed upper-tri index; invert q -> (s,t), scale by rscale,
    // store to (s,t) and (t,s).
    const int row0 = blockIdx.x * 128 + wm;
    const int col0 = blockIdx.y * 128 + wn;
    const int cl = lane & 15, rq = (lane >> 4) * 4;
    float* Ob = out + (size_t)b * NE2_ * D_;
    const float* rsb = rscale + (size_t)b * MPAD_;
    #pragma unroll
    for (int i = 0; i < 4; ++i) {
        #pragma unroll
        for (int r = 0; r < 4; ++r) {
            const int q = row0 + i*16 + rq + r;
            if (q < NTRI_) {
                // s = floor(42.5 - sqrt(42.5^2 - 2q)), with exact integer fixup
                int s = (int)(42.5f - sqrtf(1806.25f - 2.0f * (float)q));
                if (s < 0) s = 0; if (s > 41) s = 41;
                int base = (s * (85 - s)) >> 1;
                if (q < base) { --s; base = (s * (85 - s)) >> 1; }
                else { const int nb = ((s + 1) * (84 - s)) >> 1;
                       if (q >= nb) { ++s; base = nb; } }
                const int t = s + (q - base);
                const float sc = rsb[q];
                float* O1 = Ob + (size_t)(s * NE_ + t) * D_ + col0 + cl;
                float* O2 = Ob + (size_t)(t * NE_ + s) * D_ + col0 + cl;
                #pragma unroll
                for (int j = 0; j < 4; ++j) {
                    const float v = acc[i][j][r] * sc;
                    O1[j * 16] = v;
                    O2[j * 16] = v;   // diagonal double-write is harmless
                }
            }
        }
    }
}

// ---------------------------------------------------------------------------
// Workspace layout (bytes):
//   ent    : f32 [B][H][NE][L]      =  8,257,536
//   W      : bf16 [B][MPAD][L]      =  8,388,608
//   ST     : bf16 [B][D][L]         =  6,291,456
//   psum   : f32 [B][MPAD][NCH]     =  1,048,576
//   rscale : f32 [B][MPAD]          =     16,384
// total ~24 MB
// ---------------------------------------------------------------------------
#define ENT_BYTES  (8257536)
#define W_BYTES    (8388608)
#define ST_BYTES   (6291456)
#define PSUM_BYTES (1048576)

extern "C" void kernel_launch(void* const* d_in, const int* in_sizes, int n_in,
                              void* d_out, int out_size, void* d_ws, size_t ws_size,
                              hipStream_t stream) {
    const float* seq   = (const float*)d_in[0];   // [B,L,D]  f32
    const float* att   = (const float*)d_in[1];   // [B,H,L,L] f32
    const int*   midx  = (const int*)d_in[2];     // [B,NE,M]
    const int*   mmask = (const int*)d_in[3];     // [B,NE,M]
    float* out = (float*)d_out;                   // [B,NE,NE,D] f32

    char* ws  = (char*)d_ws;
    float* ent    = (float*)ws;
    u16*   W      = (u16*)(ws + ENT_BYTES);
    u16*   ST     = (u16*)(ws + ENT_BYTES + W_BYTES);
    float* psum   = (float*)(ws + ENT_BYTES + W_BYTES + ST_BYTES);
    float* rscale = (float*)(ws + ENT_BYTES + W_BYTES + ST_BYTES + PSUM_BYTES);

    ent_att_kernel<<<dim3(H_, NE_, B_), 128, 0, stream>>>(att, midx, mmask, ent);
    transpose_kernel<<<dim3(D_/32, L_/32, B_), dim3(32, 8), 0, stream>>>(seq, ST);
    gram_kernel<<<256, 256, 0, stream>>>(ent, W, psum);
    rscale_kernel<<<(B_ * NTRI_ + 255) / 256, 256, 0, stream>>>(psum, rscale);
    gemm_kernel<<<dim3(MPAD_/128, D_/128, B_), 256, 0, stream>>>(W, ST, rscale, out);
}

// Round 2
// 294.098 us; speedup vs baseline: 1.0743x; 1.0178x over previous
//
#include <hip/hip_runtime.h>
#include <math.h>

// Problem constants
#define B_    4
#define L_    1024
#define D_    768
#define H_    12
#define NE_   42
#define M_    8
#define NE2_  (NE_ * NE_)      // 1764
#define NTRI_ 903              // 42*43/2 unique (s<=t) pairs (output is symmetric)
#define MPAD_ 1024             // packed-tri rows padded for GEMM tiles
#define LC_   16               // l-chunk per gram block
#define NCH_  (L_ / LC_)       // 64 chunks

typedef unsigned short u16;
typedef unsigned int   u32;
typedef __attribute__((ext_vector_type(2))) float f32x2;

__device__ __forceinline__ u16 f2bf(float f) {
    union { float f; u32 u; } c; c.f = f;
    u32 u = c.u;
    u32 r = (u + 0x7FFFu + ((u >> 16) & 1u)) >> 16;  // round-to-nearest-even
    return (u16)r;
}

// ---------------------------------------------------------------------------
// Kernel 1 (FUSED): prep_kernel = transpose (blocks [0,TBLKS)) + ent_att
// (blocks [TBLKS, TBLKS+EBLKS)). Both roles use 256 threads; one dispatch
// instead of two (saves a launch gap).
//
// transpose role: S f32 [b][k=L][n=D] -> ST bf16 [b][n=D][k=L]
// ent role: ent[b,h,e,l] = (1/cnt) * sum_{valid m} attention[b,h,idx+1,l]
//           thread t covers l = 4t..4t+3 (one float4 per mention row)
// ---------------------------------------------------------------------------
#define TBLKS (D_/32 * L_/32 * B_)    // 24*32*4 = 3072
#define EBLKS (H_ * NE_ * B_)         // 2016

__global__ __launch_bounds__(256) void prep_kernel(
    const float* __restrict__ S, u16* __restrict__ T,
    const float* __restrict__ att, const int* __restrict__ midx,
    const int* __restrict__ mmask, float* __restrict__ ent) {
    const int bid = blockIdx.x;
    const int tid = threadIdx.x;

    if (bid < TBLKS) {
        // ---- transpose role: grid logically (D/32=24, L/32=32, B) ----
        __shared__ u16 tile[32][33];
        const int bx = bid % (D_/32);
        const int by = (bid / (D_/32)) % (L_/32);
        const int b  = bid / (D_/32 * L_/32);
        const int n0 = bx * 32, k0 = by * 32;
        const int tx = tid & 31, ty = tid >> 5;     // 32 x 8
        const float* Sb = S + (size_t)b * L_ * D_;
        u16*         Tb = T + (size_t)b * D_ * L_;
        #pragma unroll
        for (int i = 0; i < 4; ++i)
            tile[ty + i*8][tx] = f2bf(Sb[(size_t)(k0 + ty + i*8) * D_ + (n0 + tx)]);
        __syncthreads();
        #pragma unroll
        for (int i = 0; i < 4; ++i)
            Tb[(size_t)(n0 + ty + i*8) * L_ + (k0 + tx)] = tile[tx][ty + i*8];
    } else {
        // ---- ent_att role ----
        const int eb = bid - TBLKS;
        const int h  = eb % H_;
        const int e  = (eb / H_) % NE_;
        const int b  = eb / (H_ * NE_);
        const int l0 = tid * 4;
        const int mb = (b * NE_ + e) * M_;
        const size_t abase = ((size_t)(b * H_ + h)) * L_ * L_;

        float a0 = 0.f, a1 = 0.f, a2 = 0.f, a3 = 0.f;
        int cnt = 0;
        for (int m = 0; m < M_; ++m) {
            int  im = midx[mb + m] + 1;                   // OFFSET = 1
            bool v  = (mmask[mb + m] > 0) && (im < L_);
            if (v) {
                ++cnt;
                float4 x = *(const float4*)(att + abase + (size_t)im * L_ + l0);
                a0 += x.x; a1 += x.y; a2 += x.z; a3 += x.w;
            }
        }
        const float s = 1.0f / (float)(cnt < 1 ? 1 : cnt);
        float* o = ent + (((size_t)(b * H_ + h)) * NE_ + e) * L_ + l0;
        *(float4*)(o) = make_float4(a0*s, a1*s, a2*s, a3*s);
    }
}

// ---------------------------------------------------------------------------
// Kernel 2: gram_kernel. One block per (b, l-chunk of 16). Stages
// E[b,:,:,l0:l0+16] (32 KB) in LDS ONCE, computes unnormalized Gram
// G[s,t,l] = sum_h E[h,s,l]*E[h,t,l] for all s<=t pairs, packed as row
// q = s*(85-s)/2 + (t-s) in W (bf16), plus f32 per-chunk partial row sums.
// ---------------------------------------------------------------------------
__global__ __launch_bounds__(256) void gram_kernel(
    const float* __restrict__ ent,   // [B][H][NE][L] f32
    u16* __restrict__ W,             // [B][MPAD_][L] bf16, unnormalized packed-tri
    float* __restrict__ psum)        // [B][MPAD_][NCH_] f32 partial row sums
{
    __shared__ float E[H_ * NE_ * 18 + 8];   // [row=h*42+e][l: 16 used, pad to 18]
    const int gid   = blockIdx.x;            // 0..255, bijective XCD swizzle
    const int xcd   = gid & 7, rr = gid >> 3;
    const int chunk = xcd * 8 + (rr & 7);    // 0..63
    const int b     = rr >> 3;               // 0..3
    const int l0    = chunk * LC_;
    const int tid   = threadIdx.x;

    const float* Eb = ent + (size_t)b * (H_ * NE_) * L_ + l0;
    for (int i = tid; i < H_ * NE_ * 4; i += 256) {
        const int row = i >> 2, sub = (i & 3) * 4;
        float4 v = *(const float4*)(Eb + (size_t)row * L_ + sub);
        f32x2* d = (f32x2*)&E[row * 18 + sub];
        d[0] = f32x2{v.x, v.y};
        d[1] = f32x2{v.z, v.w};
    }
    __syncthreads();

    if (tid < 231) {
        const int st = tid % 21, tt = tid / 21;
        const int s0 = 2 * st, t0 = 4 * tt;
        if (s0 <= t0 + 3) {
            const int e2 = (t0 + 2 < NE_) ? t0 + 2 : NE_ - 1;
            const int e3 = (t0 + 3 < NE_) ? t0 + 3 : NE_ - 1;
            float ps[2][4] = {};
            for (int l2 = 0; l2 < LC_ / 2; ++l2) {
                const int ll = 2 * l2;
                f32x2 c[2][4] = {};
                #pragma unroll
                for (int h = 0; h < H_; ++h) {
                    const float* Eh = E + h * (NE_ * 18);
                    f32x2 a0 = *(const f32x2*)&Eh[(s0    ) * 18 + ll];
                    f32x2 a1 = *(const f32x2*)&Eh[(s0 + 1) * 18 + ll];
                    f32x2 b0 = *(const f32x2*)&Eh[(t0    ) * 18 + ll];
                    f32x2 b1 = *(const f32x2*)&Eh[(t0 + 1) * 18 + ll];
                    f32x2 b2 = *(const f32x2*)&Eh[(e2    ) * 18 + ll];
                    f32x2 b3 = *(const f32x2*)&Eh[(e3    ) * 18 + ll];
                    c[0][0] += a0 * b0; c[0][1] += a0 * b1;
                    c[0][2] += a0 * b2; c[0][3] += a0 * b3;
                    c[1][0] += a1 * b0; c[1][1] += a1 * b1;
                    c[1][2] += a1 * b2; c[1][3] += a1 * b3;
                }
                #pragma unroll
                for (int si = 0; si < 2; ++si) {
                    #pragma unroll
                    for (int tj = 0; tj < 4; ++tj) {
                        const int s = s0 + si, t = t0 + tj;
                        if (t < NE_ && s <= t) {
                            const int q = (s * (85 - s)) / 2 + (t - s);
                            u32 w = (u32)f2bf(c[si][tj][0]) |
                                    ((u32)f2bf(c[si][tj][1]) << 16);
                            *(u32*)(W + ((size_t)b * MPAD_ + q) * L_ + l0 + ll) = w;
                            ps[si][tj] += c[si][tj][0] + c[si][tj][1];
                        }
                    }
                }
            }
            #pragma unroll
            for (int si = 0; si < 2; ++si)
                #pragma unroll
                for (int tj = 0; tj < 4; ++tj) {
                    const int s = s0 + si, t = t0 + tj;
                    if (t < NE_ && s <= t) {
                        const int q = (s * (85 - s)) / 2 + (t - s);
                        psum[((size_t)b * MPAD_ + q) * NCH_ + chunk] = ps[si][tj];
                    }
                }
        }
    } else {
        // zero the 121 GEMM pad rows (903..1023) for this l-chunk; 25 threads
        for (int q = NTRI_ + (tid - 231); q < MPAD_; q += 25) {
            u16* wr = W + ((size_t)b * MPAD_ + q) * L_ + l0;
            uint4 z; z.x = z.y = z.z = z.w = 0u;
            *(uint4*)(wr)     = z;
            *(uint4*)(wr + 8) = z;
        }
    }
}

// ---------------------------------------------------------------------------
// Kernel 3: batched GEMM out = diag(rscale) * (W_packed @ S), bf16 MFMA.
// NEW vs round 1:
//  - BK=64, double-buffered LDS, 2-phase pipeline: STAGE(next) issued before
//    compute(cur); raw s_barrier + asm vmcnt(0) (NOT __syncthreads, which
//    would drain before staging overlap). 1 block/CU, so this latency was
//    previously fully exposed.
//  - T2 bank-conflict fix per rule #21: LDS dest stays linear
//    (global_load_lds requirement); the SOURCE global chunk is inverse-
//    swizzled (ko = (cp^(row&7))*8) and the ds_read applies the same XOR.
//    [128][64]-u16 rows were 8/16-way conflicts; now 2-way (free).
//  - rscale fused into prologue (threads 0..127 reduce psum rows -> LDS),
//    removing the separate rscale dispatch.
// grid (8, 6, B) = 192 blocks.
// ---------------------------------------------------------------------------
typedef __attribute__((ext_vector_type(8))) __bf16 bf16x8;
typedef __attribute__((ext_vector_type(4))) float  f32x4;

__global__ __launch_bounds__(256) void gemm_kernel(
    const u16* __restrict__ W, const u16* __restrict__ T,
    const float* __restrict__ psum, float* __restrict__ out) {
    __shared__ __align__(16) u16 As[2][128 * 64];
    __shared__ __align__(16) u16 Bs[2][128 * 64];
    __shared__ float rs_s[128];
    const int b = blockIdx.z;
    const u16* Ab = W + (size_t)b * MPAD_ * L_ + (size_t)blockIdx.x * 128 * L_;
    const u16* Bb = T + (size_t)b * D_   * L_ + (size_t)blockIdx.y * 128 * L_;
    const int tid  = threadIdx.x;
    const int wave = tid >> 6, lane = tid & 63;
    const int wm = (wave & 1) * 64, wn = (wave >> 1) * 64;
    const int rm = lane & 15, kq = (lane >> 4) * 8;

    // stage one 128x64 bf16 tile per operand; 8 chunks of 16B per row,
    // source chunk XOR-swizzled so the linear LDS dest holds swizzled layout
    auto STAGE = [&](int buf, int k0) {
        #pragma unroll
        for (int i = 0; i < 4; ++i) {
            const int c   = i * 256 + tid;        // 1024 chunks = 128 rows x 8
            const int row = c >> 3, cp = c & 7;
            const int ko  = ((cp ^ (row & 7)) << 3);
            __builtin_amdgcn_global_load_lds(
                (const __attribute__((address_space(1))) void*)(Ab + (size_t)row * L_ + k0 + ko),
                (__attribute__((address_space(3))) void*)(&As[buf][c * 8]), 16, 0, 0);
            __builtin_amdgcn_global_load_lds(
                (const __attribute__((address_space(1))) void*)(Bb + (size_t)row * L_ + k0 + ko),
                (__attribute__((address_space(3))) void*)(&Bs[buf][c * 8]), 16, 0, 0);
        }
    };

    f32x4 acc[4][4] = {};

    // ---- prologue: first tile + fused rscale reduction (overlapped) ----
    STAGE(0, 0);
    if (tid < 128) {
        const float* p = psum + ((size_t)b * MPAD_ + (size_t)blockIdx.x * 128 + tid) * NCH_;
        float s = 0.f;
        #pragma unroll
        for (int i = 0; i < NCH_ / 4; ++i) {
            float4 v = *(const float4*)(p + 4 * i);
            s += v.x + v.y + v.z + v.w;
        }
        rs_s[tid] = 1.0f / (s + (float)H_ * 1e-5f);   // pad rows: garbage, unused
    }
    asm volatile("s_waitcnt vmcnt(0) lgkmcnt(0)" ::: "memory");
    __builtin_amdgcn_s_barrier();

    // ---- main loop: 16 K-tiles of 64 ----
    int cur = 0;
    for (int kt = 0; kt < 16; ++kt) {
        if (kt < 15) STAGE(cur ^ 1, (kt + 1) * 64);   // issue next-tile loads

        #pragma unroll
        for (int kk = 0; kk < 64; kk += 32) {
            bf16x8 af[4], bfr[4];
            #pragma unroll
            for (int i = 0; i < 4; ++i) {
                const int ra = wm + i*16 + rm;
                af[i]  = *(const bf16x8*)&As[cur][ra * 64 + ((((kk + kq) >> 3) ^ (ra & 7)) << 3)];
            }
            #pragma unroll
            for (int j = 0; j < 4; ++j) {
                const int rb = wn + j*16 + rm;
                bfr[j] = *(const bf16x8*)&Bs[cur][rb * 64 + ((((kk + kq) >> 3) ^ (rb & 7)) << 3)];
            }
            #pragma unroll
            for (int i = 0; i < 4; ++i)
                #pragma unroll
                for (int j = 0; j < 4; ++j)
                    acc[i][j] = __builtin_amdgcn_mfma_f32_16x16x32_bf16(
                                    af[i], bfr[j], acc[i][j], 0, 0, 0);
        }

        asm volatile("s_waitcnt vmcnt(0)" ::: "memory");   // next tile landed
        __builtin_amdgcn_s_barrier();                      // all threads' loads visible
        cur ^= 1;
    }

    // ---- epilogue: C/D layout col = lane&15, row = (lane>>4)*4 + reg ----
    // Row q is packed upper-tri; invert q -> (s,t), scale, write (s,t) & (t,s).
    const int row0 = blockIdx.x * 128 + wm;
    const int col0 = blockIdx.y * 128 + wn;
    const int cl = lane & 15, rq = (lane >> 4) * 4;
    float* Ob = out + (size_t)b * NE2_ * D_;
    #pragma unroll
    for (int i = 0; i < 4; ++i) {
        #pragma unroll
        for (int r = 0; r < 4; ++r) {
            const int q = row0 + i*16 + rq + r;
            if (q < NTRI_) {
                int s = (int)(42.5f - sqrtf(1806.25f - 2.0f * (float)q));
                if (s < 0) s = 0; if (s > 41) s = 41;
                int base = (s * (85 - s)) >> 1;
                if (q < base) { --s; base = (s * (85 - s)) >> 1; }
                else { const int nb = ((s + 1) * (84 - s)) >> 1;
                       if (q >= nb) { ++s; base = nb; } }
                const int t = s + (q - base);
                const float sc = rs_s[q - blockIdx.x * 128];
                float* O1 = Ob + (size_t)(s * NE_ + t) * D_ + col0 + cl;
                float* O2 = Ob + (size_t)(t * NE_ + s) * D_ + col0 + cl;
                #pragma unroll
                for (int j = 0; j < 4; ++j) {
                    const float v = acc[i][j][r] * sc;
                    O1[j * 16] = v;
                    O2[j * 16] = v;   // diagonal double-write is harmless
                }
            }
        }
    }
}

// ---------------------------------------------------------------------------
// Workspace layout (bytes):
//   ent  : f32 [B][H][NE][L]   =  8,257,536
//   W    : bf16 [B][MPAD][L]   =  8,388,608
//   ST   : bf16 [B][D][L]      =  6,291,456
//   psum : f32 [B][MPAD][NCH]  =  1,048,576
// total ~24 MB
// ---------------------------------------------------------------------------
#define ENT_BYTES  (8257536)
#define W_BYTES    (8388608)
#define ST_BYTES   (6291456)

extern "C" void kernel_launch(void* const* d_in, const int* in_sizes, int n_in,
                              void* d_out, int out_size, void* d_ws, size_t ws_size,
                              hipStream_t stream) {
    const float* seq   = (const float*)d_in[0];   // [B,L,D]  f32
    const float* att   = (const float*)d_in[1];   // [B,H,L,L] f32
    const int*   midx  = (const int*)d_in[2];     // [B,NE,M]
    const int*   mmask = (const int*)d_in[3];     // [B,NE,M]
    float* out = (float*)d_out;                   // [B,NE,NE,D] f32

    char* ws  = (char*)d_ws;
    float* ent  = (float*)ws;
    u16*   Wb   = (u16*)(ws + ENT_BYTES);
    u16*   ST   = (u16*)(ws + ENT_BYTES + W_BYTES);
    float* psum = (float*)(ws + ENT_BYTES + W_BYTES + ST_BYTES);

    prep_kernel<<<TBLKS + EBLKS, 256, 0, stream>>>(seq, ST, att, midx, mmask, ent);
    gram_kernel<<<256, 256, 0, stream>>>(ent, Wb, psum);
    gemm_kernel<<<dim3(MPAD_/128, D_/128, B_), 256, 0, stream>>>(Wb, ST, psum, out);
}